// Round 3
// baseline (1026.464 us; speedup 1.0000x reference)
//
#include <hip/hip_runtime.h>
#include <hip/hip_bf16.h>
#include <math.h>

#define NUM_EXPERTS 8
#define NTOK 8192
#define CDIM 1024
#define FDIM 4096
#define MAXSLOTS 18432   /* 16384 slots + 8*256 pad */
#define MAXTILES 72      /* 8 XCDs x 9 tiles of 256 rows */
#define TILES_PER_XCD 9

typedef __bf16 bf16x8 __attribute__((ext_vector_type(8)));
typedef float  f32x4  __attribute__((ext_vector_type(4)));

#define GPTR(p) ((const __attribute__((address_space(1))) unsigned int*)(p))
#define LPTR(p) ((__attribute__((address_space(3))) unsigned int*)(p))
#define MFMA16(b, a, c) __builtin_amdgcn_mfma_f32_16x16x32_bf16((b), (a), (c), 0, 0, 0)

__device__ __forceinline__ float gelu_exact(float v){
  return 0.5f * v * (1.0f + erff(v * 0.70710678118654752f));
}
__device__ __forceinline__ float bf2f(unsigned short u){
  union { unsigned int i; float f; } cv; cv.i = ((unsigned int)u) << 16; return cv.f;
}

// ---------------- router: logits -> top2 -> weights + counts ----------------
__global__ __launch_bounds__(256) void moe_router(
    const float* __restrict__ x, const float* __restrict__ gw,
    int2* __restrict__ topi, float2* __restrict__ topw, int* __restrict__ counts)
{
  int token = blockIdx.x * 4 + (threadIdx.x >> 6);
  int lane  = threadIdx.x & 63;
  int e = lane & 7, part = lane >> 3;
  const float* xr = x + (size_t)token * CDIM;
  float s = 0.f;
  int c0 = part * 128;
  for (int c = c0; c < c0 + 128; ++c) s += xr[c] * gw[c * 8 + e];
  s += __shfl_xor(s, 8); s += __shfl_xor(s, 16); s += __shfl_xor(s, 32);
  float m1 = s; int i1 = e;
  for (int off = 1; off < 8; off <<= 1){
    float ov = __shfl_xor(m1, off); int oi = __shfl_xor(i1, off);
    if (ov > m1 || (ov == m1 && oi < i1)){ m1 = ov; i1 = oi; }
  }
  float l2 = (e == i1) ? -INFINITY : s;
  float m2 = l2; int i2 = e;
  for (int off = 1; off < 8; off <<= 1){
    float ov = __shfl_xor(m2, off); int oi = __shfl_xor(i2, off);
    if (ov > m2 || (ov == m2 && oi < i2)){ m2 = ov; i2 = oi; }
  }
  if (lane == 0){
    float r = expf(m2 - m1);          // p2/p1
    float wa = 1.f / (1.f + r);
    topi[token] = make_int2(i1, i2);
    topw[token] = make_float2(wa, 1.f - wa);
    atomicAdd(&counts[i1], 1);
    atomicAdd(&counts[i2], 1);
  }
}

// ---------------- x fp32 -> bf16 ----------------
__global__ __launch_bounds__(256) void convert_x_kernel(
    const float* __restrict__ x, __hip_bfloat16* __restrict__ xb)
{
  int i = (blockIdx.x * 256 + threadIdx.x) * 4;
  float4 v = *(const float4*)(x + i);
  union { __hip_bfloat16 hh[4]; ushort4 u; } cv;
  cv.hh[0] = __float2bfloat16(v.x);
  cv.hh[1] = __float2bfloat16(v.y);
  cv.hh[2] = __float2bfloat16(v.z);
  cv.hh[3] = __float2bfloat16(v.w);
  *(ushort4*)(xb + i) = cv.u;
}

// ---------------- weight transpose+convert: [z][R][Cc] fp32 -> [z][Cc][R] bf16 ----
__global__ __launch_bounds__(256) void transpose_bf16_kernel(
    const float* __restrict__ in, __hip_bfloat16* __restrict__ outp, int R, int Cc)
{
  __shared__ __hip_bfloat16 tile[64 * 66];
  const size_t msz = (size_t)R * Cc;
  const float* inm = in + (size_t)blockIdx.z * msz;
  __hip_bfloat16* outm = outp + (size_t)blockIdx.z * msz;
  int r0 = blockIdx.y * 64, c0 = blockIdx.x * 64;
  int t = threadIdx.x;
  int r = t & 63, cseg = (t >> 6) * 16;
  const float* src = inm + (size_t)(r0 + r) * Cc + c0 + cseg;
  float4 v0 = ((const float4*)src)[0];
  float4 v1 = ((const float4*)src)[1];
  float4 v2 = ((const float4*)src)[2];
  float4 v3 = ((const float4*)src)[3];
  float vv[16] = {v0.x,v0.y,v0.z,v0.w, v1.x,v1.y,v1.z,v1.w,
                  v2.x,v2.y,v2.z,v2.w, v3.x,v3.y,v3.z,v3.w};
#pragma unroll
  for (int k = 0; k < 16; ++k)
    tile[(cseg + k) * 66 + r] = __float2bfloat16(vv[k]);
  __syncthreads();
#pragma unroll
  for (int p = 0; p < 2; ++p){
    int cc = p * 32 + (t >> 3), ch = (t & 7) * 8;
    const unsigned short* rowp = (const unsigned short*)tile + cc * 66 + ch;
    unsigned int a = *(const unsigned int*)(rowp + 0);
    unsigned int b = *(const unsigned int*)(rowp + 2);
    unsigned int c = *(const unsigned int*)(rowp + 4);
    unsigned int d = *(const unsigned int*)(rowp + 6);
    *(uint4*)(outm + (size_t)(c0 + cc) * R + r0 + ch) = make_uint4(a, b, c, d);
  }
}

// ---------------- scan: expert offsets (256-aligned), tile table, pad fill ----------------
__global__ void scan_kernel(const int* __restrict__ counts, int* cursors, int* num_tiles,
    int* tile_expert, int* tile_slotbase, int* slot_token, float* slot_weight)
{
  int t = threadIdx.x;
  if (t == 0){
    int base = 0, T = 0;
    for (int e = 0; e < NUM_EXPERTS; ++e){
      cursors[e] = base;
      int nt = (counts[e] + 255) >> 8;
      for (int i = 0; i < nt; ++i){ tile_expert[T] = e; tile_slotbase[T] = base + i * 256; ++T; }
      base += nt << 8;
    }
    *num_tiles = T;
  }
  for (int i = t; i < MAXSLOTS; i += 256){ slot_token[i] = 0; slot_weight[i] = 0.f; }
}

// ---------------- assign (token,k) -> slot; record token -> slots ----------------
__global__ void assign_kernel(const int2* __restrict__ topi, const float2* __restrict__ topw,
    int* cursors, int* slot_token, float* slot_weight, int2* __restrict__ token_slots)
{
  int token = blockIdx.x * 256 + threadIdx.x;
  int2 ii = topi[token];
  float2 ww = topw[token];
  int p0 = atomicAdd(&cursors[ii.x], 1);
  slot_token[p0] = token; slot_weight[p0] = ww.x;
  int p1 = atomicAdd(&cursors[ii.y], 1);
  slot_token[p1] = token; slot_weight[p1] = ww.y;
  token_slots[token] = make_int2(p0, p1);
}

// ---------------- 8-phase 256x256 grouped GEMM (m201 schedule port) ----------------
// BM=BN=256, BK=64, 8 waves (2Mx4N), per-wave 128x64 out, acc[8][4].
// LDS 128KB = 2-parity dbuf x (A 32KB + B 32KB). Group-interleaved rows:
// group g holds tile rows {g*32..g*32+31} U {128+g*32..+31} so phase q's
// dead region (group q-1) is one contiguous 8KB piece -> staged by the
// 2 global_load_lds of phase q, 2 K-tiles ahead. Counted vmcnt(6) once per
// K-tile (T4); setprio around each 16-MFMA cluster (T5); XOR chunk swizzle
// baked into staging source (T2, rule #21).
template<int KD, int ND, bool G1>
__global__ __launch_bounds__(512, 2) void moe_gemm(
    const __hip_bfloat16* __restrict__ A, const __hip_bfloat16* __restrict__ Bw,
    __hip_bfloat16* __restrict__ Out,
    const int* __restrict__ num_tiles, const int* __restrict__ tile_expert,
    const int* __restrict__ tile_slotbase, const int* __restrict__ slot_token)
{
  constexpr int NT = KD / 64;          // K-tiles of BK=64
  constexpr int NBLK = ND / 256;       // N-panels of 256
  __shared__ __align__(16) char smem[131072];
  const int L = blockIdx.x;
  const int xcd = L & 7;
  const int jdec = L >> 3;
  const int tl = jdec / NBLK;
  const int nb = jdec % NBLK;
  const int tm = xcd * TILES_PER_XCD + tl;
  if (tm >= *num_tiles) return;
  const int e = tile_expert[tm];
  const int sbase = tile_slotbase[tm];
  const int n0 = nb * 256;
  const int t = threadIdx.x;
  const int lane = t & 63, wid = t >> 6;
  const int wm = wid >> 2, wn = wid & 3;      // 2 x 4 wave grid
  const int lr = lane & 15, lq = lane >> 4;

  // ---- staging: piece g = 8KB = 64 LDS rows; thread t -> LDS row t>>3,
  // chunk t&7; holds tile row sub*128 + g*32 + rr, global chunk pre-swizzled.
  const int lr6 = t >> 3;                    // 0..63
  const int sub = lr6 >> 5, rr = lr6 & 31;
  const int sch = (t & 7) ^ (rr & 7);
  const __hip_bfloat16* sA[4];
  const __hip_bfloat16* sB[4];
#pragma unroll
  for (int g = 0; g < 4; ++g){
    int trow = sub * 128 + g * 32 + rr;
    int ar = G1 ? slot_token[sbase + trow] : (sbase + trow);
    sA[g] = A + (size_t)ar * KD + sch * 8;
    sB[g] = Bw + ((size_t)e * ND + n0 + trow) * KD + sch * 8;
  }
  char* dA = smem + wid * 1024;              // + par*32768 + g*8192 (lane*16 by HW)
  char* dB = smem + 65536 + wid * 1024;

#define STG(gg, ktt) do{ const int par_ = (ktt) & 1; \
    __builtin_amdgcn_global_load_lds(GPTR(sA[gg] + (size_t)(ktt) * 64), LPTR(dA + par_ * 32768 + (gg) * 8192), 16, 0, 0); \
    __builtin_amdgcn_global_load_lds(GPTR(sB[gg] + (size_t)(ktt) * 64), LPTR(dB + par_ * 32768 + (gg) * 8192), 16, 0, 0); }while(0)

  // ---- read offsets (group-interleaved rows, XOR chunk swizzle) ----
  int offA[8], offB[4];
#pragma unroll
  for (int f = 0; f < 8; ++f)
    offA[f] = ((f >> 1) * 64 + wm * 32 + (f & 1) * 16 + lr) * 128;
#pragma unroll
  for (int j = 0; j < 4; ++j)
    offB[j] = (((wn & 1) * 2 + (j >> 1)) * 64 + (wn >> 1) * 32 + (j & 1) * 16 + lr) * 128;
  const int swz0 = ((0 + lq) ^ (lr & 7)) * 16;   // k-chunks 0..3
  const int swz1 = ((4 + lq) ^ (lr & 7)) * 16;   // k-chunks 4..7

  // ---- prologue: K-tiles 0 and 1 fully staged; wait tile 0 (8 newest = tile 1)
  STG(0, 0); STG(1, 0); STG(2, 0); STG(3, 0);
  STG(0, 1); STG(1, 1); STG(2, 1); STG(3, 1);
  f32x4 acc[8][4] = {};
  asm volatile("s_waitcnt vmcnt(8)" ::: "memory");
  __builtin_amdgcn_s_barrier();

  bf16x8 bB[4][2];
  for (int kt = 0; kt < NT; ++kt){
    const int par = kt & 1;
    const char* pA = smem + par * 32768;
    const char* pB = smem + 65536 + par * 32768;
#pragma unroll
    for (int q = 0; q < 4; ++q){
      if (q == 0){
#pragma unroll
        for (int j = 0; j < 4; ++j){
          bB[j][0] = *(const bf16x8*)(pB + offB[j] + swz0);
          bB[j][1] = *(const bf16x8*)(pB + offB[j] + swz1);
        }
      }
      bf16x8 a00 = *(const bf16x8*)(pA + offA[2*q]     + swz0);
      bf16x8 a01 = *(const bf16x8*)(pA + offA[2*q]     + swz1);
      bf16x8 a10 = *(const bf16x8*)(pA + offA[2*q + 1] + swz0);
      bf16x8 a11 = *(const bf16x8*)(pA + offA[2*q + 1] + swz1);
      // stage the piece that died last phase, 2 K-tiles ahead
      const int ktt = (q == 0) ? (kt + 1) : (kt + 2);
      const int gg = (q + 3) & 3;
      if (ktt >= 2 && ktt < NT) STG(gg, ktt);
      __builtin_amdgcn_s_barrier();
      __builtin_amdgcn_s_setprio(1);
#pragma unroll
      for (int j = 0; j < 4; ++j){
        acc[2*q][j]     = MFMA16(bB[j][0], a00, acc[2*q][j]);
        acc[2*q + 1][j] = MFMA16(bB[j][0], a10, acc[2*q + 1][j]);
      }
#pragma unroll
      for (int j = 0; j < 4; ++j){
        acc[2*q][j]     = MFMA16(bB[j][1], a01, acc[2*q][j]);
        acc[2*q + 1][j] = MFMA16(bB[j][1], a11, acc[2*q + 1][j]);
      }
      __builtin_amdgcn_s_setprio(0);
      if (q == 3){
        if (kt < NT - 2) asm volatile("s_waitcnt vmcnt(6)" ::: "memory");
        else             asm volatile("s_waitcnt vmcnt(0)" ::: "memory");
      }
      if (!(kt == NT - 1 && q == 3)) __builtin_amdgcn_s_barrier();
    }
  }
#undef STG

  // ---- epilogue: lane holds 4 consecutive output cols per row (verified r2) ----
  const int orow0 = sbase + wm * 128 + lr;
  const int ocol0 = n0 + wn * 64 + lq * 4;
#pragma unroll
  for (int f = 0; f < 8; ++f){
    __hip_bfloat16* orow = Out + (size_t)(orow0 + f * 16) * ND + ocol0;
#pragma unroll
    for (int j = 0; j < 4; ++j){
      f32x4 v = acc[f][j];
      union { __hip_bfloat16 h4[4]; ushort4 u; } cv;
      if (G1){
        cv.h4[0] = __float2bfloat16(gelu_exact(v[0]));
        cv.h4[1] = __float2bfloat16(gelu_exact(v[1]));
        cv.h4[2] = __float2bfloat16(gelu_exact(v[2]));
        cv.h4[3] = __float2bfloat16(gelu_exact(v[3]));
      } else {
        cv.h4[0] = __float2bfloat16(v[0]);
        cv.h4[1] = __float2bfloat16(v[1]);
        cv.h4[2] = __float2bfloat16(v[2]);
        cv.h4[3] = __float2bfloat16(v[3]);
      }
      *(ushort4*)(orow + j * 16) = cv.u;
    }
  }
}

// ---------------- combine: out[token] = w0*y[s0] + w1*y[s1] ----------------
__global__ __launch_bounds__(256) void combine_kernel(
    const __hip_bfloat16* __restrict__ y, const int2* __restrict__ token_slots,
    const float* __restrict__ slot_weight, float* __restrict__ out)
{
  int token = blockIdx.x;
  int c = threadIdx.x * 4;
  int2 ss = token_slots[token];
  float w0 = slot_weight[ss.x], w1 = slot_weight[ss.y];
  ushort4 a = *(const ushort4*)((const unsigned short*)y + (size_t)ss.x * CDIM + c);
  ushort4 b = *(const ushort4*)((const unsigned short*)y + (size_t)ss.y * CDIM + c);
  float4 o;
  o.x = w0 * bf2f(a.x) + w1 * bf2f(b.x);
  o.y = w0 * bf2f(a.y) + w1 * bf2f(b.y);
  o.z = w0 * bf2f(a.z) + w1 * bf2f(b.z);
  o.w = w0 * bf2f(a.w) + w1 * bf2f(b.w);
  *(float4*)(out + (size_t)token * CDIM + c) = o;
}

// ---------------- slow-but-correct fallback (ws too small) ----------------
__global__ __launch_bounds__(256) void naive_kernel(
    const float* __restrict__ x, const float* __restrict__ w1, const float* __restrict__ w2,
    const int2* __restrict__ topi, const float2* __restrict__ topw, float* __restrict__ out)
{
  __shared__ float xs[CDIM];
  __shared__ float hs[FDIM];
  int token = blockIdx.x;
  int t = threadIdx.x;
  for (int i = t; i < CDIM; i += 256) xs[i] = x[(size_t)token * CDIM + i];
  float acc[4] = {0.f, 0.f, 0.f, 0.f};
  int2 ei = topi[token]; float2 ew = topw[token];
  int elist[2] = {ei.x, ei.y}; float wlist[2] = {ew.x, ew.y};
  for (int kk = 0; kk < 2; ++kk){
    int e = elist[kk]; float wgt = wlist[kk];
    __syncthreads();
    for (int f = t; f < FDIM; f += 256){
      const float* wcol = w1 + (size_t)e * CDIM * FDIM + f;
      float s = 0.f;
      for (int c = 0; c < CDIM; ++c) s += xs[c] * wcol[(size_t)c * FDIM];
      hs[f] = gelu_exact(s);
    }
    __syncthreads();
    for (int ii = 0; ii < 4; ++ii){
      int c = ii * 256 + t;
      const float* w2col = w2 + (size_t)e * FDIM * CDIM + c;
      float s = 0.f;
      for (int f = 0; f < FDIM; ++f) s += hs[f] * w2col[(size_t)f * CDIM];
      acc[ii] += wgt * s;
    }
  }
  for (int ii = 0; ii < 4; ++ii) out[(size_t)token * CDIM + ii * 256 + t] = acc[ii];
}

extern "C" void kernel_launch(void* const* d_in, const int* in_sizes, int n_in,
                              void* d_out, int out_size, void* d_ws, size_t ws_size,
                              hipStream_t stream)
{
  const float* x  = (const float*)d_in[0];
  const float* gw = (const float*)d_in[1];
  const float* w1 = (const float*)d_in[2];
  const float* w2 = (const float*)d_in[3];
  float* out = (float*)d_out;
  char* ws = (char*)d_ws;

  int*    counts        = (int*)(ws + 0);
  int*    cursors       = (int*)(ws + 32);
  int*    num_tiles     = (int*)(ws + 64);
  int*    tile_expert   = (int*)(ws + 256);
  int*    tile_slotbase = (int*)(ws + 1024);
  int2*   topi          = (int2*)(ws + 4096);
  float2* topw          = (float2*)(ws + 69632);
  int*    slot_token    = (int*)(ws + 135168);   /* 18432*4 = 73728 -> ends 208896 */
  float*  slot_weight   = (float*)(ws + 208896); /* 73728 -> ends 282624 */
  int2*   token_slots   = (int2*)(ws + 282624);  /* 65536 -> ends 348160 */
  const size_t XBF_OFF = 1u << 20;
  const size_t W1T_OFF = XBF_OFF + (size_t)NTOK * CDIM * 2;
  const size_t W2T_OFF = W1T_OFF + (size_t)NUM_EXPERTS * CDIM * FDIM * 2;
  const size_t H_OFF   = W2T_OFF + (size_t)NUM_EXPERTS * CDIM * FDIM * 2;
  const size_t NEED    = H_OFF + (size_t)MAXSLOTS * FDIM * 2;                  // ~289 MB
  __hip_bfloat16* xbf = (__hip_bfloat16*)(ws + XBF_OFF);
  __hip_bfloat16* w1t = (__hip_bfloat16*)(ws + W1T_OFF);
  __hip_bfloat16* w2t = (__hip_bfloat16*)(ws + W2T_OFF);
  __hip_bfloat16* h   = (__hip_bfloat16*)(ws + H_OFF);
  __hip_bfloat16* y   = (__hip_bfloat16*)(ws + W1T_OFF);  // overlays w1t (dead after gemm1)

  hipMemsetAsync(ws, 0, 4096, stream);

  moe_router<<<NTOK / 4, 256, 0, stream>>>(x, gw, topi, topw, counts);

  if (ws_size >= NEED){
    convert_x_kernel<<<NTOK * CDIM / (4 * 256), 256, 0, stream>>>(x, xbf);
    transpose_bf16_kernel<<<dim3(FDIM / 64, CDIM / 64, NUM_EXPERTS), 256, 0, stream>>>(w1, w1t, CDIM, FDIM);
    transpose_bf16_kernel<<<dim3(CDIM / 64, FDIM / 64, NUM_EXPERTS), 256, 0, stream>>>(w2, w2t, FDIM, CDIM);
    scan_kernel<<<1, 256, 0, stream>>>(counts, cursors, num_tiles, tile_expert, tile_slotbase, slot_token, slot_weight);
    assign_kernel<<<NTOK / 256, 256, 0, stream>>>(topi, topw, cursors, slot_token, slot_weight, token_slots);
    moe_gemm<CDIM, FDIM, true ><<<8 * TILES_PER_XCD * (FDIM / 256), 512, 0, stream>>>(
        xbf, w1t, h, num_tiles, tile_expert, tile_slotbase, slot_token);
    moe_gemm<FDIM, CDIM, false><<<8 * TILES_PER_XCD * (CDIM / 256), 512, 0, stream>>>(
        h, w2t, y, num_tiles, tile_expert, tile_slotbase, slot_token);
    combine_kernel<<<NTOK, 256, 0, stream>>>(y, token_slots, slot_weight, out);
  } else {
    naive_kernel<<<NTOK, 256, 0, stream>>>(x, w1, w2, topi, topw, out);
  }
}